// Round 7
// baseline (742.863 us; speedup 1.0000x reference)
//
#include <hip/hip_runtime.h>

// ============================================================================
// ROUND-7 DIAGNOSTIC BUILD: every kernel's work is amplified (31x small
// kernels, 9x attn) so each dispatch exceeds the ~40us harness poison fills
// and appears in rocprof's top-5 with true dur_us + counters. Outputs are
// bit-identical (idempotent re-execution; attn's 9x scaling cancels in the
// softmax normalization). Round 8 reverts REPS to 1.
// ============================================================================
#define SMALL_REPS 31
#define ATTN_REPS 9

typedef short bf16x4 __attribute__((ext_vector_type(4)));
typedef short bf16x8 __attribute__((ext_vector_type(8)));
typedef float f32x4 __attribute__((ext_vector_type(4)));
typedef unsigned short u16x4 __attribute__((ext_vector_type(4)));
typedef unsigned short u16x8 __attribute__((ext_vector_type(8)));

__device__ __forceinline__ unsigned short f2bf(float f) {
  union { float f; unsigned u; } v; v.f = f;
  unsigned r = v.u + 0x7FFFu + ((v.u >> 16) & 1u);
  return (unsigned short)(r >> 16);
}
__device__ __forceinline__ unsigned fbits(float f) {
  union { float f; unsigned u; } x; x.f = f; return x.u;
}
__device__ __forceinline__ float bfloat(unsigned u) {
  union { unsigned u; float f; } x; x.u = u; return x.f;
}
__device__ __forceinline__ float fexp2(float x) {
#if __has_builtin(__builtin_amdgcn_exp2f)
  return __builtin_amdgcn_exp2f(x);
#else
  return exp2f(x);
#endif
}
__device__ __forceinline__ f32x4 pv_mfma(bf16x4 a, bf16x4 b, f32x4 c) {
#if __has_builtin(__builtin_amdgcn_mfma_f32_16x16x16bf16_1k)
  return __builtin_amdgcn_mfma_f32_16x16x16bf16_1k(a, b, c, 0, 0, 0);
#else
  bf16x8 az = {a[0], a[1], a[2], a[3], 0, 0, 0, 0};
  bf16x8 bz = {b[0], b[1], b[2], b[3], 0, 0, 0, 0};
  return __builtin_amdgcn_mfma_f32_16x16x32_bf16(az, bz, c, 0, 0, 0);
#endif
}

// ---------- cast/transpose (+ weight casts) ----------
__global__ __launch_bounds__(256)
void cast_kernel(const float* __restrict__ Xq_, const float* __restrict__ Xkv_,
                 const float* __restrict__ Wqkv_, const float* __restrict__ Wproj_,
                 unsigned short* __restrict__ XT_, unsigned short* __restrict__ Wq16_,
                 unsigned short* __restrict__ Wph_, unsigned short* __restrict__ Wpl_)
{
  __shared__ __align__(16) float Tl[64][68];
  const int b = blockIdx.x, t = threadIdx.x;
  #pragma unroll 1
  for (int rep = 0; rep < SMALL_REPS; ++rep) {
    const float* Xq = Xq_;  const float* Xkv = Xkv_;
    const float* Wqkv = Wqkv_; const float* Wproj = Wproj_;
    unsigned short* XT = XT_; unsigned short* Wq16 = Wq16_;
    unsigned short* Wph = Wph_; unsigned short* Wpl = Wpl_;
    asm volatile("" : "+s"(Xq), "+s"(Xkv), "+s"(Wqkv), "+s"(Wproj),
                      "+s"(XT), "+s"(Wq16), "+s"(Wph), "+s"(Wpl));
    __syncthreads();   // WAR guard on Tl across reps
    if (b < 256) {
      const int img = b >> 7, kt = (b >> 6) & 1, nt = b & 63;
      const float* X = img ? Xkv : Xq;
      #pragma unroll
      for (int i = 0; i < 4; ++i) {
        int e = i * 256 + t;
        int r = e >> 4, c4 = (e & 15) * 4;
        *(f32x4*)&Tl[r][c4] = *(const f32x4*)&X[(kt * 64 + r) * 4096 + nt * 64 + c4];
      }
      __syncthreads();
      unsigned short* out = XT + img * (4096 * 128);
      #pragma unroll
      for (int i = 0; i < 2; ++i) {
        int u = i * 256 + t;
        int n = u >> 3, kg = u & 7;
        u16x8 tv;
        #pragma unroll
        for (int j = 0; j < 8; ++j) tv[j] = f2bf(Tl[kg * 8 + j][n]);
        *(u16x8*)&out[(nt * 64 + n) * 128 + kt * 64 + kg * 8] = tv;
      }
    } else {
      const int wb = b - 256;
      if (wb < 3) {
        #pragma unroll 4
        for (int i = 0; i < 64; ++i) {
          int idx = wb * 16384 + i * 256 + t;
          Wq16[idx] = f2bf(Wqkv[idx]);
        }
      } else {
        #pragma unroll 4
        for (int i = 0; i < 64; ++i) {
          int idx = i * 256 + t;
          float v = Wproj[idx];
          unsigned short h = f2bf(v);
          float hf = bfloat((unsigned)h << 16);
          Wph[idx] = h;
          Wpl[idx] = f2bf(v - hf);
        }
      }
    }
  }
}

// ---------- qkv GEMM: all-register MFMA, bf16 output ----------
__global__ __launch_bounds__(256)
void gemm_qkv_kernel(const unsigned short* __restrict__ XT_,
                     const unsigned short* __restrict__ Wq16_,
                     unsigned short* __restrict__ Y16_)
{
  const int t = threadIdx.x;
  const int w = t >> 6, c = t & 15, g = (t & 63) >> 4;
  const int n0 = blockIdx.x * 32;
  const int ob = blockIdx.y;
  const int o_base = ob * 64 + w * 16;
  #pragma unroll 1
  for (int rep = 0; rep < SMALL_REPS; ++rep) {
    const unsigned short* XT = XT_;
    const unsigned short* Wq16 = Wq16_;
    unsigned short* Y16 = Y16_;
    asm volatile("" : "+s"(XT), "+s"(Wq16), "+s"(Y16));
    const unsigned short* B = XT + (ob >= 2 ? 4096 * 128 : 0);
    f32x4 acc0 = {0.f, 0.f, 0.f, 0.f}, acc1 = {0.f, 0.f, 0.f, 0.f};
    #pragma unroll
    for (int ks = 0; ks < 4; ++ks) {
      bf16x8 a = *(const bf16x8*)&Wq16[(o_base + c) * 128 + ks * 32 + g * 8];
      bf16x8 b0 = *(const bf16x8*)&B[(n0 + c) * 128 + ks * 32 + g * 8];
      bf16x8 b1 = *(const bf16x8*)&B[(n0 + 16 + c) * 128 + ks * 32 + g * 8];
      acc0 = __builtin_amdgcn_mfma_f32_16x16x32_bf16(a, b0, acc0, 0, 0, 0);
      acc1 = __builtin_amdgcn_mfma_f32_16x16x32_bf16(a, b1, acc1, 0, 0, 0);
    }
    #pragma unroll
    for (int i = 0; i < 4; ++i) {
      Y16[(o_base + 4 * g + i) * 4096 + n0 + c] = f2bf(acc0[i]);
      Y16[(o_base + 4 * g + i) * 4096 + n0 + 16 + c] = f2bf(acc1[i]);
    }
  }
}

// ---------- proj GEMM, split-bf16 (hi+lo) ----------
__global__ __launch_bounds__(256)
void gemm_proj_kernel(const unsigned short* __restrict__ Oth_,
                      const unsigned short* __restrict__ Otl_,
                      const unsigned short* __restrict__ Wph_,
                      const unsigned short* __restrict__ Wpl_, float* __restrict__ Y_)
{
  const int t = threadIdx.x;
  const int w = t >> 6, c = t & 15, g = (t & 63) >> 4;
  const int n0 = blockIdx.x * 32;
  const int o_base = blockIdx.y * 64 + w * 16;
  #pragma unroll 1
  for (int rep = 0; rep < SMALL_REPS; ++rep) {
    const unsigned short* Oth = Oth_; const unsigned short* Otl = Otl_;
    const unsigned short* Wph = Wph_; const unsigned short* Wpl = Wpl_;
    float* Y = Y_;
    asm volatile("" : "+s"(Oth), "+s"(Otl), "+s"(Wph), "+s"(Wpl), "+s"(Y));
    f32x4 acc0 = {0.f, 0.f, 0.f, 0.f}, acc1 = {0.f, 0.f, 0.f, 0.f};
    #pragma unroll
    for (int ks = 0; ks < 4; ++ks) {
      const int ko = ks * 32 + g * 8;
      bf16x8 ah = *(const bf16x8*)&Wph[(o_base + c) * 128 + ko];
      bf16x8 al = *(const bf16x8*)&Wpl[(o_base + c) * 128 + ko];
      bf16x8 bh0 = *(const bf16x8*)&Oth[(n0 + c) * 128 + ko];
      bf16x8 bl0 = *(const bf16x8*)&Otl[(n0 + c) * 128 + ko];
      bf16x8 bh1 = *(const bf16x8*)&Oth[(n0 + 16 + c) * 128 + ko];
      bf16x8 bl1 = *(const bf16x8*)&Otl[(n0 + 16 + c) * 128 + ko];
      acc0 = __builtin_amdgcn_mfma_f32_16x16x32_bf16(al, bh0, acc0, 0, 0, 0);
      acc0 = __builtin_amdgcn_mfma_f32_16x16x32_bf16(ah, bl0, acc0, 0, 0, 0);
      acc0 = __builtin_amdgcn_mfma_f32_16x16x32_bf16(ah, bh0, acc0, 0, 0, 0);
      acc1 = __builtin_amdgcn_mfma_f32_16x16x32_bf16(al, bh1, acc1, 0, 0, 0);
      acc1 = __builtin_amdgcn_mfma_f32_16x16x32_bf16(ah, bl1, acc1, 0, 0, 0);
      acc1 = __builtin_amdgcn_mfma_f32_16x16x32_bf16(ah, bh1, acc1, 0, 0, 0);
    }
    #pragma unroll
    for (int i = 0; i < 4; ++i) {
      Y[(o_base + 4 * g + i) * 4096 + n0 + c] = acc0[i];
      Y[(o_base + 4 * g + i) * 4096 + n0 + 16 + c] = acc1[i];
    }
  }
}

// ---------- depthwise 3x3 (q/k transposed out, v channel-major) ----------
__global__ __launch_bounds__(256)
void dwconv_kernel(const unsigned short* __restrict__ T16_, const float* __restrict__ Wd_,
                   const float* __restrict__ temp_, unsigned short* __restrict__ Qt_,
                   unsigned short* __restrict__ Kt_, unsigned short* __restrict__ Vb_)
{
  __shared__ __align__(16) float P[4096];
  const int jc = blockIdx.x;
  const int t = threadIdx.x;
  #pragma unroll 1
  for (int rep = 0; rep < SMALL_REPS; ++rep) {
    const unsigned short* T16 = T16_; const float* Wd = Wd_; const float* temp = temp_;
    unsigned short* Qt = Qt_; unsigned short* Kt = Kt_; unsigned short* Vb = Vb_;
    asm volatile("" : "+s"(T16), "+s"(Wd), "+s"(temp), "+s"(Qt), "+s"(Kt), "+s"(Vb));
    __syncthreads();   // WAR guard on P across reps
    const unsigned short* in = T16 + jc * 4096;
    #pragma unroll
    for (int i = 0; i < 2; ++i) {
      u16x8 v = *(const u16x8*)&in[(i * 256 + t) * 8];
      #pragma unroll
      for (int j = 0; j < 8; ++j)
        P[(i * 256 + t) * 8 + j] = bfloat((unsigned)v[j] << 16);
    }
    float w[9];
    #pragma unroll
    for (int k = 0; k < 9; ++k) w[k] = Wd[jc * 9 + k];
    const float scale = (jc < 128) ? temp[jc >> 5] * 1.4426950408889634f : 1.0f;
    __syncthreads();

    const int hh = (jc >> 5) & 3, dd = jc & 31;
    unsigned short* outT = (jc < 128 ? Qt : Kt) + (hh * 4096) * 32 + dd;
    unsigned short* outV = Vb + (jc - 256) * 4096;
    const bool is_v = (jc >= 256);

    #pragma unroll 4
    for (int i = 0; i < 16; ++i) {
      int idx = i * 256 + t;
      int y = idx >> 6, x = idx & 63;
      float acc = 0.f;
      #pragma unroll
      for (int dy = -1; dy <= 1; ++dy) {
        int yy = y + dy;
        if (yy < 0 || yy > 63) continue;
        #pragma unroll
        for (int dx = -1; dx <= 1; ++dx) {
          int xx = x + dx;
          if (xx < 0 || xx > 63) continue;
          acc += w[(dy + 1) * 3 + (dx + 1)] * P[yy * 64 + xx];
        }
      }
      unsigned short r = f2bf(acc * scale);
      if (is_v) outV[idx] = r;
      else      outT[idx * 32] = r;
    }
  }
}

// ----------------------- flash attention (bf16 MFMA) -----------------------
// ATTN_REPS x the key loop: oh and lsum scale identically; O = oh/lsum is
// invariant. Epilogue unchanged, executed once.
__global__ __launch_bounds__(1024, 4)
void attn_kernel(const unsigned short* __restrict__ Qt,
                 const unsigned short* __restrict__ Kt,
                 const unsigned short* __restrict__ Vb,
                 unsigned short* __restrict__ Oth, unsigned short* __restrict__ Otl)
{
  __shared__ __align__(16) char lds[40960];
  const int t = threadIdx.x;
  const int wv = t >> 6;
  const int g4 = wv >> 2, qw = wv & 3;
  const int l = t & 63;
  const int c = l & 15, g = l >> 4;
  const int h = blockIdx.y;
  const int nq = blockIdx.x * 64;
  const int m0w = wv * 256;

  bf16x8 qf[4];
  #pragma unroll
  for (int s = 0; s < 4; ++s)
    qf[s] = *(const bf16x8*)&Qt[(h * 4096 + nq + s * 16 + c) * 32 + g * 8];

  f32x4 oh[4][2];
  #pragma unroll
  for (int s = 0; s < 4; ++s) {
    oh[s][0] = (f32x4){0.f, 0.f, 0.f, 0.f};
    oh[s][1] = (f32x4){0.f, 0.f, 0.f, 0.f};
  }
  float lsum[4] = {0.f, 0.f, 0.f, 0.f};

  const unsigned short* Kb  = Kt + (h * 4096 + m0w + c) * 32 + g * 8;
  const unsigned short* Vb0 = Vb + (h * 32 + c) * 4096 + m0w + g * 4;
  const unsigned short* Vb1 = Vb0 + 16 * 4096;

  #pragma unroll 1
  for (int rep = 0; rep < ATTN_REPS; ++rep) {
    const unsigned short* Kbr = Kb;
    const unsigned short* V0r = Vb0;
    const unsigned short* V1r = Vb1;
    asm volatile("" : "+v"(Kbr), "+v"(V0r), "+v"(V1r));
    #pragma unroll 4
    for (int j = 0; j < 16; ++j) {
      bf16x8 kf = *(const bf16x8*)&Kbr[j * 512];
      bf16x4 vf0 = *(const bf16x4*)&V0r[j * 16];
      bf16x4 vf1 = *(const bf16x4*)&V1r[j * 16];
      #pragma unroll
      for (int s = 0; s < 4; ++s) {
        f32x4 z = {0.f, 0.f, 0.f, 0.f};
        f32x4 sv = __builtin_amdgcn_mfma_f32_16x16x32_bf16(kf, qf[s], z, 0, 0, 0);
        float e0 = fexp2(sv[0]);
        float e1 = fexp2(sv[1]);
        float e2 = fexp2(sv[2]);
        float e3 = fexp2(sv[3]);
        lsum[s] += (e0 + e1) + (e2 + e3);
        union { unsigned u[2]; bf16x4 v; } pu;
        pu.u[0] = __builtin_amdgcn_perm(fbits(e1), fbits(e0), 0x07060302);
        pu.u[1] = __builtin_amdgcn_perm(fbits(e3), fbits(e2), 0x07060302);
        oh[s][0] = pv_mfma(vf0, pu.v, oh[s][0]);
        oh[s][1] = pv_mfma(vf1, pu.v, oh[s][1]);
      }
    }
  }

  #pragma unroll
  for (int s = 0; s < 4; ++s) {
    lsum[s] += __shfl_xor(lsum[s], 16, 64);
    lsum[s] += __shfl_xor(lsum[s], 32, 64);
  }

  __syncthreads();
  float* OG  = (float*)lds;               // [4][32][66]
  float* lfq = (float*)(lds + 34048);     // [64]
  float* lf  = (float*)(lds + 36864);     // [16][64]
  if (l < 16) {
    #pragma unroll
    for (int s = 0; s < 4; ++s)
      lf[(g4 * 4 + qw) * 64 + s * 16 + c] = lsum[s];
  }
  for (int r = 0; r < 4; ++r) {
    if (qw == r) {
      #pragma unroll
      for (int s = 0; s < 4; ++s)
        #pragma unroll
        for (int i = 0; i < 4; ++i) {
          int d0 = 4 * g + i;
          float* p0 = &OG[g4 * 2112 + d0 * 66 + s * 16 + c];
          float* p1 = &OG[g4 * 2112 + (16 + d0) * 66 + s * 16 + c];
          if (r == 0) { *p0 = oh[s][0][i];  *p1 = oh[s][1][i]; }
          else        { *p0 += oh[s][0][i]; *p1 += oh[s][1][i]; }
        }
    }
    __syncthreads();
  }
  if (t < 64) {
    float a = 0.f;
    #pragma unroll
    for (int ww = 0; ww < 16; ++ww) a += lf[ww * 64 + t];
    lfq[t] = a;
  }
  __syncthreads();

  #pragma unroll
  for (int e = t; e < 2048; e += 1024) {
    int d = e & 31, q = e >> 5;
    float s4 = OG[0 * 2112 + d * 66 + q] + OG[1 * 2112 + d * 66 + q] +
               OG[2 * 2112 + d * 66 + q] + OG[3 * 2112 + d * 66 + q];
    float val = s4 / lfq[q];
    unsigned short hi = f2bf(val);
    float hf = bfloat((unsigned)hi << 16);
    int idx = (blockIdx.x * 64 + q) * 128 + h * 32 + d;
    Oth[idx] = hi;
    Otl[idx] = f2bf(val - hf);
  }
}

extern "C" void kernel_launch(void* const* d_in, const int* in_sizes, int n_in,
                              void* d_out, int out_size, void* d_ws, size_t ws_size,
                              hipStream_t stream) {
  const float* xq    = (const float*)d_in[0];
  const float* xkv   = (const float*)d_in[1];
  const float* wqkv  = (const float*)d_in[2];
  const float* wdw   = (const float*)d_in[3];
  const float* wproj = (const float*)d_in[4];
  const float* temp  = (const float*)d_in[5];
  float* out = (float*)d_out;

  char* ws = (char*)d_ws;
  unsigned short* t16  = (unsigned short*)ws;                  // 3 MB
  unsigned short* xt   = (unsigned short*)(ws + 3145728);      // 2 MB
  unsigned short* wq16 = (unsigned short*)(ws + 5242880);      // 96 KB
  unsigned short* wph  = (unsigned short*)(ws + 5341184);      // 32 KB
  unsigned short* wpl  = (unsigned short*)(ws + 5373952);      // 32 KB
  unsigned short* qt   = (unsigned short*)(ws + 5406720);      // 1 MB
  unsigned short* kt   = (unsigned short*)(ws + 6455296);      // 1 MB
  unsigned short* vb   = (unsigned short*)(ws + 7503872);      // 1 MB
  unsigned short* oth  = (unsigned short*)(ws + 8552448);      // 1 MB
  unsigned short* otl  = (unsigned short*)(ws + 9601024);      // 1 MB

  cast_kernel<<<dim3(260), 256, 0, stream>>>(xq, xkv, wqkv, wproj, xt, wq16, wph, wpl);
  gemm_qkv_kernel<<<dim3(128, 6), 256, 0, stream>>>(xt, wq16, t16);
  dwconv_kernel<<<dim3(384), 256, 0, stream>>>(t16, wdw, temp, qt, kt, vb);
  attn_kernel<<<dim3(64, 4), 1024, 0, stream>>>(qt, kt, vb, oth, otl);
  gemm_proj_kernel<<<dim3(128, 2), 256, 0, stream>>>(oth, otl, wph, wpl, out);
}

// Round 8
// 90.805 us; speedup vs baseline: 8.1809x; 8.1809x over previous
//
#include <hip/hip_runtime.h>

typedef short bf16x4 __attribute__((ext_vector_type(4)));
typedef short bf16x8 __attribute__((ext_vector_type(8)));
typedef float f32x4 __attribute__((ext_vector_type(4)));
typedef unsigned short u16x4 __attribute__((ext_vector_type(4)));
typedef unsigned short u16x8 __attribute__((ext_vector_type(8)));

__device__ __forceinline__ unsigned short f2bf(float f) {
  union { float f; unsigned u; } v; v.f = f;
  unsigned r = v.u + 0x7FFFu + ((v.u >> 16) & 1u);
  return (unsigned short)(r >> 16);
}
__device__ __forceinline__ unsigned fbits(float f) {
  union { float f; unsigned u; } x; x.f = f; return x.u;
}
__device__ __forceinline__ float bfloat(unsigned u) {
  union { unsigned u; float f; } x; x.u = u; return x.f;
}
__device__ __forceinline__ float fexp2(float x) {
#if __has_builtin(__builtin_amdgcn_exp2f)
  return __builtin_amdgcn_exp2f(x);
#else
  return exp2f(x);
#endif
}
// RNE packed f32->2xbf16 (verified on gfx950, learn_hip m214v22)
__device__ __forceinline__ unsigned cvt_pk_bf16(float a, float b) {
  unsigned r;
  asm("v_cvt_pk_bf16_f32 %0, %1, %2" : "=v"(r) : "v"(a), "v"(b));
  return r;
}
__device__ __forceinline__ f32x4 pv_mfma(bf16x4 a, bf16x4 b, f32x4 c) {
#if __has_builtin(__builtin_amdgcn_mfma_f32_16x16x16bf16_1k)
  return __builtin_amdgcn_mfma_f32_16x16x16bf16_1k(a, b, c, 0, 0, 0);
#else
  bf16x8 az = {a[0], a[1], a[2], a[3], 0, 0, 0, 0};
  bf16x8 bz = {b[0], b[1], b[2], b[3], 0, 0, 0, 0};
  return __builtin_amdgcn_mfma_f32_16x16x32_bf16(az, bz, c, 0, 0, 0);
#endif
}

// ---------- fused qkv: in-block X transpose+cast (LDS f32) + W cast + MFMA ----
// Y16[o][n] bf16, o in [ob*64, ob*64+64), n tile 32. ob 0..1 read Xq, 2..5 Xkv.
__global__ __launch_bounds__(256)
void qkvT_kernel(const float* __restrict__ Xq, const float* __restrict__ Xkv,
                 const float* __restrict__ Wqkv, unsigned short* __restrict__ Y16)
{
  __shared__ float Xf[128][33];   // [k][n], +1 pad
  const int t = threadIdx.x;
  const int w = t >> 6, c = t & 15, g = (t & 63) >> 4;
  const int n0 = blockIdx.x * 32;
  const int ob = blockIdx.y;
  const float* X = (ob >= 2) ? Xkv : Xq;

  // stage X tile [128 k][32 n] f32 (coalesced rows -> scalar LDS writes)
  {
    const int kr = t >> 3;
    const int nc = (t & 7) * 4;
    #pragma unroll
    for (int pass = 0; pass < 4; ++pass) {
      int k = pass * 32 + kr;
      f32x4 v = *(const f32x4*)&X[k * 4096 + n0 + nc];
      Xf[k][nc + 0] = v[0];
      Xf[k][nc + 1] = v[1];
      Xf[k][nc + 2] = v[2];
      Xf[k][nc + 3] = v[3];
    }
  }

  // A-frags from W f32 (global, RNE cvt_pk)
  union { unsigned u[4]; bf16x8 v; } af[4];
  {
    const float* wr = Wqkv + (ob * 64 + w * 16 + c) * 128;
    #pragma unroll
    for (int ks = 0; ks < 4; ++ks) {
      f32x4 v0 = *(const f32x4*)&wr[ks * 32 + g * 8];
      f32x4 v1 = *(const f32x4*)&wr[ks * 32 + g * 8 + 4];
      af[ks].u[0] = cvt_pk_bf16(v0[0], v0[1]);
      af[ks].u[1] = cvt_pk_bf16(v0[2], v0[3]);
      af[ks].u[2] = cvt_pk_bf16(v1[0], v1[1]);
      af[ks].u[3] = cvt_pk_bf16(v1[2], v1[3]);
    }
  }
  __syncthreads();

  // B-frags from LDS (scalar f32 reads, 2-way conflicts max) + cvt_pk
  union { unsigned u[4]; bf16x8 v; } bfr[2][4];
  #pragma unroll
  for (int s = 0; s < 2; ++s) {
    const int n = s * 16 + c;
    #pragma unroll
    for (int ks = 0; ks < 4; ++ks) {
      const int kb = ks * 32 + g * 8;
      #pragma unroll
      for (int m = 0; m < 4; ++m)
        bfr[s][ks].u[m] = cvt_pk_bf16(Xf[kb + 2 * m][n], Xf[kb + 2 * m + 1][n]);
    }
  }

  f32x4 acc[2] = {{0.f, 0.f, 0.f, 0.f}, {0.f, 0.f, 0.f, 0.f}};
  #pragma unroll
  for (int ks = 0; ks < 4; ++ks) {
    acc[0] = __builtin_amdgcn_mfma_f32_16x16x32_bf16(af[ks].v, bfr[0][ks].v, acc[0], 0, 0, 0);
    acc[1] = __builtin_amdgcn_mfma_f32_16x16x32_bf16(af[ks].v, bfr[1][ks].v, acc[1], 0, 0, 0);
  }
  #pragma unroll
  for (int s = 0; s < 2; ++s)
    #pragma unroll
    for (int i = 0; i < 4; ++i)
      Y16[(ob * 64 + w * 16 + 4 * g + i) * 4096 + n0 + s * 16 + c] = f2bf(acc[s][i]);
}

// ---------- depthwise 3x3 SAME, quarter-plane blocks (occupancy fix) --------
// grid 1536: block = (channel jc, quarter qtr). 18-row halo staged in LDS f32.
// q/k outputs scatter to Qt/Kt [h][pos][32]; v linear to Vb [ch][pos].
__global__ __launch_bounds__(256)
void dwconv_kernel(const unsigned short* __restrict__ T16, const float* __restrict__ Wd,
                   const float* __restrict__ temp, unsigned short* __restrict__ Qt,
                   unsigned short* __restrict__ Kt, unsigned short* __restrict__ Vb)
{
  __shared__ float P[18 * 64];
  const int jc = blockIdx.x >> 2;
  const int qtr = blockIdx.x & 3;
  const int y0 = qtr * 16;
  const int t = threadIdx.x;
  const unsigned short* in = T16 + jc * 4096;
  #pragma unroll
  for (int i = 0; i < 5; ++i) {
    int idx = i * 256 + t;
    if (idx < 1152) {
      int row = idx >> 6, col = idx & 63;
      int sy = y0 - 1 + row;
      P[idx] = (sy >= 0 && sy < 64) ? bfloat((unsigned)in[sy * 64 + col] << 16) : 0.f;
    }
  }
  float w[9];
  #pragma unroll
  for (int k = 0; k < 9; ++k) w[k] = Wd[jc * 9 + k];
  const float scale = (jc < 128) ? temp[jc >> 5] * 1.4426950408889634f : 1.0f;
  __syncthreads();

  const int hh = (jc >> 5) & 3, dd = jc & 31;
  unsigned short* outT = (jc < 128 ? Qt : Kt) + hh * 4096 * 32 + dd;
  unsigned short* outV = Vb + (jc - 256) * 4096 + y0 * 64;
  const bool is_v = (jc >= 256);

  #pragma unroll
  for (int i = 0; i < 4; ++i) {
    int p = i * 256 + t;
    int yl = p >> 6, x = p & 63;
    float acc = 0.f;
    #pragma unroll
    for (int dy = 0; dy < 3; ++dy) {
      int base = (yl + dy) * 64 + x;
      if (x > 0)  acc += w[dy * 3 + 0] * P[base - 1];
      acc += w[dy * 3 + 1] * P[base];
      if (x < 63) acc += w[dy * 3 + 2] * P[base + 1];
    }
    unsigned short r = f2bf(acc * scale);
    if (is_v) outV[p] = r;
    else      outT[(y0 * 64 + p) * 32] = r;
  }
}

// ----------------------- flash attention (bf16 MFMA) -----------------------
// Barrier-free trans-bound main loop (R6, unchanged). New epilogue: zero-init
// + ds_add_f32 atomics into one [32][66] buffer, 2 barriers total (was 6).
__global__ __launch_bounds__(1024, 4)
void attn_kernel(const unsigned short* __restrict__ Qt,
                 const unsigned short* __restrict__ Kt,
                 const unsigned short* __restrict__ Vb,
                 unsigned short* __restrict__ Oth, unsigned short* __restrict__ Otl)
{
  __shared__ __align__(16) char lds[12544];
  const int t = threadIdx.x;
  const int wv = t >> 6;
  const int l = t & 63;
  const int c = l & 15, g = l >> 4;
  const int h = blockIdx.y;
  const int nq = blockIdx.x * 64;
  const int m0w = wv * 256;

  bf16x8 qf[4];
  #pragma unroll
  for (int s = 0; s < 4; ++s)
    qf[s] = *(const bf16x8*)&Qt[(h * 4096 + nq + s * 16 + c) * 32 + g * 8];

  f32x4 oh[4][2];
  #pragma unroll
  for (int s = 0; s < 4; ++s) {
    oh[s][0] = (f32x4){0.f, 0.f, 0.f, 0.f};
    oh[s][1] = (f32x4){0.f, 0.f, 0.f, 0.f};
  }
  float lsum[4] = {0.f, 0.f, 0.f, 0.f};

  const unsigned short* Kb  = Kt + (h * 4096 + m0w + c) * 32 + g * 8;
  const unsigned short* Vb0 = Vb + (h * 32 + c) * 4096 + m0w + g * 4;
  const unsigned short* Vb1 = Vb0 + 16 * 4096;

  #pragma unroll 4
  for (int j = 0; j < 16; ++j) {
    bf16x8 kf = *(const bf16x8*)&Kb[j * 512];
    bf16x4 vf0 = *(const bf16x4*)&Vb0[j * 16];
    bf16x4 vf1 = *(const bf16x4*)&Vb1[j * 16];
    #pragma unroll
    for (int s = 0; s < 4; ++s) {
      f32x4 z = {0.f, 0.f, 0.f, 0.f};
      f32x4 sv = __builtin_amdgcn_mfma_f32_16x16x32_bf16(kf, qf[s], z, 0, 0, 0);
      float e0 = fexp2(sv[0]);
      float e1 = fexp2(sv[1]);
      float e2 = fexp2(sv[2]);
      float e3 = fexp2(sv[3]);
      lsum[s] += (e0 + e1) + (e2 + e3);
      union { unsigned u[2]; bf16x4 v; } pu;
      pu.u[0] = __builtin_amdgcn_perm(fbits(e1), fbits(e0), 0x07060302);
      pu.u[1] = __builtin_amdgcn_perm(fbits(e3), fbits(e2), 0x07060302);
      oh[s][0] = pv_mfma(vf0, pu.v, oh[s][0]);
      oh[s][1] = pv_mfma(vf1, pu.v, oh[s][1]);
    }
  }

  #pragma unroll
  for (int s = 0; s < 4; ++s) {
    lsum[s] += __shfl_xor(lsum[s], 16, 64);
    lsum[s] += __shfl_xor(lsum[s], 32, 64);
  }

  float* OG = (float*)lds;                 // [32][66] f32 accumulator
  float* lf = (float*)(lds + 8448);        // [16][64] per-wave lsum
  #pragma unroll
  for (int e = t; e < 2112; e += 1024) OG[e] = 0.f;
  if (l < 16) {
    #pragma unroll
    for (int s = 0; s < 4; ++s)
      lf[wv * 64 + s * 16 + c] = lsum[s];
  }
  __syncthreads();
  #pragma unroll
  for (int s = 0; s < 4; ++s)
    #pragma unroll
    for (int i = 0; i < 4; ++i) {
      int d0 = 4 * g + i;
      unsafeAtomicAdd(&OG[d0 * 66 + s * 16 + c], oh[s][0][i]);
      unsafeAtomicAdd(&OG[(16 + d0) * 66 + s * 16 + c], oh[s][1][i]);
    }
  __syncthreads();

  #pragma unroll
  for (int e = t; e < 2048; e += 1024) {
    int d = e & 31, q = e >> 5;
    float li = 0.f;
    #pragma unroll
    for (int ww = 0; ww < 16; ++ww) li += lf[ww * 64 + q];
    float val = OG[d * 66 + q] / li;
    unsigned short hi = f2bf(val);
    float hf = bfloat((unsigned)hi << 16);
    int idx = (blockIdx.x * 64 + q) * 128 + h * 32 + d;
    Oth[idx] = hi;
    Otl[idx] = f2bf(val - hf);
  }
}

// ---------- proj GEMM, split-bf16, W cast folded in-block ----------
__global__ __launch_bounds__(256)
void gemm_proj_kernel(const unsigned short* __restrict__ Oth,
                      const unsigned short* __restrict__ Otl,
                      const float* __restrict__ Wp, float* __restrict__ Y)
{
  const int t = threadIdx.x;
  const int w = t >> 6, c = t & 15, g = (t & 63) >> 4;
  const int n0 = blockIdx.x * 32;
  const int o_base = blockIdx.y * 64 + w * 16;
  f32x4 acc0 = {0.f, 0.f, 0.f, 0.f}, acc1 = {0.f, 0.f, 0.f, 0.f};
  #pragma unroll
  for (int ks = 0; ks < 4; ++ks) {
    const int ko = ks * 32 + g * 8;
    const float* wr = Wp + (o_base + c) * 128 + ko;
    union { unsigned u[4]; bf16x8 v; } ah, al;
    #pragma unroll
    for (int m = 0; m < 2; ++m) {
      f32x4 v = *(const f32x4*)&wr[m * 4];
      #pragma unroll
      for (int p = 0; p < 2; ++p) {
        unsigned hw = cvt_pk_bf16(v[2 * p], v[2 * p + 1]);
        float h0 = bfloat(hw << 16);
        float h1 = bfloat(hw & 0xFFFF0000u);
        ah.u[m * 2 + p] = hw;
        al.u[m * 2 + p] = cvt_pk_bf16(v[2 * p] - h0, v[2 * p + 1] - h1);
      }
    }
    bf16x8 bh0 = *(const bf16x8*)&Oth[(n0 + c) * 128 + ko];
    bf16x8 bl0 = *(const bf16x8*)&Otl[(n0 + c) * 128 + ko];
    bf16x8 bh1 = *(const bf16x8*)&Oth[(n0 + 16 + c) * 128 + ko];
    bf16x8 bl1 = *(const bf16x8*)&Otl[(n0 + 16 + c) * 128 + ko];
    acc0 = __builtin_amdgcn_mfma_f32_16x16x32_bf16(al.v, bh0, acc0, 0, 0, 0);
    acc0 = __builtin_amdgcn_mfma_f32_16x16x32_bf16(ah.v, bl0, acc0, 0, 0, 0);
    acc0 = __builtin_amdgcn_mfma_f32_16x16x32_bf16(ah.v, bh0, acc0, 0, 0, 0);
    acc1 = __builtin_amdgcn_mfma_f32_16x16x32_bf16(al.v, bh1, acc1, 0, 0, 0);
    acc1 = __builtin_amdgcn_mfma_f32_16x16x32_bf16(ah.v, bl1, acc1, 0, 0, 0);
    acc1 = __builtin_amdgcn_mfma_f32_16x16x32_bf16(ah.v, bh1, acc1, 0, 0, 0);
  }
  #pragma unroll
  for (int i = 0; i < 4; ++i) {
    Y[(o_base + 4 * g + i) * 4096 + n0 + c] = acc0[i];
    Y[(o_base + 4 * g + i) * 4096 + n0 + 16 + c] = acc1[i];
  }
}

extern "C" void kernel_launch(void* const* d_in, const int* in_sizes, int n_in,
                              void* d_out, int out_size, void* d_ws, size_t ws_size,
                              hipStream_t stream) {
  const float* xq    = (const float*)d_in[0];
  const float* xkv   = (const float*)d_in[1];
  const float* wqkv  = (const float*)d_in[2];
  const float* wdw   = (const float*)d_in[3];
  const float* wproj = (const float*)d_in[4];
  const float* temp  = (const float*)d_in[5];
  float* out = (float*)d_out;

  char* ws = (char*)d_ws;
  unsigned short* t16 = (unsigned short*)ws;                 // 3 MB  [384][4096]
  unsigned short* qt  = (unsigned short*)(ws + 3145728);     // 1 MB  [4][4096][32]
  unsigned short* kt  = (unsigned short*)(ws + 4194304);     // 1 MB
  unsigned short* vb  = (unsigned short*)(ws + 5242880);     // 1 MB  [128][4096]
  unsigned short* oth = (unsigned short*)(ws + 6291456);     // 1 MB  [4096][128]
  unsigned short* otl = (unsigned short*)(ws + 7340032);     // 1 MB

  qkvT_kernel<<<dim3(128, 6), 256, 0, stream>>>(xq, xkv, wqkv, t16);
  dwconv_kernel<<<dim3(1536), 256, 0, stream>>>(t16, wdw, temp, qt, kt, vb);
  attn_kernel<<<dim3(64, 4), 1024, 0, stream>>>(qt, kt, vb, oth, otl);
  gemm_proj_kernel<<<dim3(128, 2), 256, 0, stream>>>(oth, otl, wproj, out);
}

// Round 9
// 51.172 us; speedup vs baseline: 14.5171x; 1.7745x over previous
//
#include <hip/hip_runtime.h>

typedef short bf16x4 __attribute__((ext_vector_type(4)));
typedef short bf16x8 __attribute__((ext_vector_type(8)));
typedef float f32x4 __attribute__((ext_vector_type(4)));
typedef unsigned short u16x4 __attribute__((ext_vector_type(4)));
typedef unsigned short u16x8 __attribute__((ext_vector_type(8)));

__device__ __forceinline__ unsigned short f2bf(float f) {
  union { float f; unsigned u; } v; v.f = f;
  unsigned r = v.u + 0x7FFFu + ((v.u >> 16) & 1u);
  return (unsigned short)(r >> 16);
}
__device__ __forceinline__ unsigned fbits(float f) {
  union { float f; unsigned u; } x; x.f = f; return x.u;
}
__device__ __forceinline__ float bfloat(unsigned u) {
  union { unsigned u; float f; } x; x.u = u; return x.f;
}
__device__ __forceinline__ float fexp2(float x) {
#if __has_builtin(__builtin_amdgcn_exp2f)
  return __builtin_amdgcn_exp2f(x);
#else
  return exp2f(x);
#endif
}
// RNE packed f32->2xbf16 (verified on gfx950)
__device__ __forceinline__ unsigned cvt_pk_bf16(float a, float b) {
  unsigned r;
  asm("v_cvt_pk_bf16_f32 %0, %1, %2" : "=v"(r) : "v"(a), "v"(b));
  return r;
}
__device__ __forceinline__ f32x4 pv_mfma(bf16x4 a, bf16x4 b, f32x4 c) {
#if __has_builtin(__builtin_amdgcn_mfma_f32_16x16x16bf16_1k)
  return __builtin_amdgcn_mfma_f32_16x16x16bf16_1k(a, b, c, 0, 0, 0);
#else
  bf16x8 az = {a[0], a[1], a[2], a[3], 0, 0, 0, 0};
  bf16x8 bz = {b[0], b[1], b[2], b[3], 0, 0, 0, 0};
  return __builtin_amdgcn_mfma_f32_16x16x32_bf16(az, bz, c, 0, 0, 0);
#endif
}

// ---------- fused qkv: in-block X transpose+cast (LDS f32) + W cast + MFMA ----
__global__ __launch_bounds__(256)
void qkvT_kernel(const float* __restrict__ Xq, const float* __restrict__ Xkv,
                 const float* __restrict__ Wqkv, unsigned short* __restrict__ Y16)
{
  __shared__ float Xf[128][33];
  const int t = threadIdx.x;
  const int w = t >> 6, c = t & 15, g = (t & 63) >> 4;
  const int n0 = blockIdx.x * 32;
  const int ob = blockIdx.y;
  const float* X = (ob >= 2) ? Xkv : Xq;

  {
    const int kr = t >> 3;
    const int nc = (t & 7) * 4;
    #pragma unroll
    for (int pass = 0; pass < 4; ++pass) {
      int k = pass * 32 + kr;
      f32x4 v = *(const f32x4*)&X[k * 4096 + n0 + nc];
      Xf[k][nc + 0] = v[0];
      Xf[k][nc + 1] = v[1];
      Xf[k][nc + 2] = v[2];
      Xf[k][nc + 3] = v[3];
    }
  }

  union { unsigned u[4]; bf16x8 v; } af[4];
  {
    const float* wr = Wqkv + (ob * 64 + w * 16 + c) * 128;
    #pragma unroll
    for (int ks = 0; ks < 4; ++ks) {
      f32x4 v0 = *(const f32x4*)&wr[ks * 32 + g * 8];
      f32x4 v1 = *(const f32x4*)&wr[ks * 32 + g * 8 + 4];
      af[ks].u[0] = cvt_pk_bf16(v0[0], v0[1]);
      af[ks].u[1] = cvt_pk_bf16(v0[2], v0[3]);
      af[ks].u[2] = cvt_pk_bf16(v1[0], v1[1]);
      af[ks].u[3] = cvt_pk_bf16(v1[2], v1[3]);
    }
  }
  __syncthreads();

  union { unsigned u[4]; bf16x8 v; } bfr[2][4];
  #pragma unroll
  for (int s = 0; s < 2; ++s) {
    const int n = s * 16 + c;
    #pragma unroll
    for (int ks = 0; ks < 4; ++ks) {
      const int kb = ks * 32 + g * 8;
      #pragma unroll
      for (int m = 0; m < 4; ++m)
        bfr[s][ks].u[m] = cvt_pk_bf16(Xf[kb + 2 * m][n], Xf[kb + 2 * m + 1][n]);
    }
  }

  f32x4 acc[2] = {{0.f, 0.f, 0.f, 0.f}, {0.f, 0.f, 0.f, 0.f}};
  #pragma unroll
  for (int ks = 0; ks < 4; ++ks) {
    acc[0] = __builtin_amdgcn_mfma_f32_16x16x32_bf16(af[ks].v, bfr[0][ks].v, acc[0], 0, 0, 0);
    acc[1] = __builtin_amdgcn_mfma_f32_16x16x32_bf16(af[ks].v, bfr[1][ks].v, acc[1], 0, 0, 0);
  }
  #pragma unroll
  for (int s = 0; s < 2; ++s)
    #pragma unroll
    for (int i = 0; i < 4; ++i)
      Y16[(ob * 64 + w * 16 + 4 * g + i) * 4096 + n0 + s * 16 + c] = f2bf(acc[s][i]);
}

// ---------- depthwise 3x3 SAME, quarter-plane blocks ----------
__global__ __launch_bounds__(256)
void dwconv_kernel(const unsigned short* __restrict__ T16, const float* __restrict__ Wd,
                   const float* __restrict__ temp, unsigned short* __restrict__ Qt,
                   unsigned short* __restrict__ Kt, unsigned short* __restrict__ Vb)
{
  __shared__ float P[18 * 64];
  const int jc = blockIdx.x >> 2;
  const int qtr = blockIdx.x & 3;
  const int y0 = qtr * 16;
  const int t = threadIdx.x;
  const unsigned short* in = T16 + jc * 4096;
  #pragma unroll
  for (int i = 0; i < 5; ++i) {
    int idx = i * 256 + t;
    if (idx < 1152) {
      int row = idx >> 6, col = idx & 63;
      int sy = y0 - 1 + row;
      P[idx] = (sy >= 0 && sy < 64) ? bfloat((unsigned)in[sy * 64 + col] << 16) : 0.f;
    }
  }
  float w[9];
  #pragma unroll
  for (int k = 0; k < 9; ++k) w[k] = Wd[jc * 9 + k];
  const float scale = (jc < 128) ? temp[jc >> 5] * 1.4426950408889634f : 1.0f;
  __syncthreads();

  const int hh = (jc >> 5) & 3, dd = jc & 31;
  unsigned short* outT = (jc < 128 ? Qt : Kt) + hh * 4096 * 32 + dd;
  unsigned short* outV = Vb + (jc - 256) * 4096 + y0 * 64;
  const bool is_v = (jc >= 256);

  #pragma unroll
  for (int i = 0; i < 4; ++i) {
    int p = i * 256 + t;
    int yl = p >> 6, x = p & 63;
    float acc = 0.f;
    #pragma unroll
    for (int dy = 0; dy < 3; ++dy) {
      int base = (yl + dy) * 64 + x;
      if (x > 0)  acc += w[dy * 3 + 0] * P[base - 1];
      acc += w[dy * 3 + 1] * P[base];
      if (x < 63) acc += w[dy * 3 + 2] * P[base + 1];
    }
    unsigned short r = f2bf(acc * scale);
    if (is_v) outV[p] = r;
    else      outT[(y0 * 64 + p) * 32] = r;
  }
}

// ----------------------- flash attention (bf16 MFMA) -----------------------
// Barrier-free main loop (unchanged). Epilogue: 3-barrier binary-tree register
// reduction across the 16 waves (each wave's oh covers the full 32d x 64q
// tile; waves differ only in key range). No atomics.
__global__ __launch_bounds__(1024, 4)
void attn_kernel(const unsigned short* __restrict__ Qt,
                 const unsigned short* __restrict__ Kt,
                 const unsigned short* __restrict__ Vb,
                 unsigned short* __restrict__ Oth, unsigned short* __restrict__ Otl)
{
  extern __shared__ __align__(16) char lds[];
  float* WS = (float*)lds;                 // 8 slots x 2048 f32 (64 KB)
  float* lf = (float*)(lds + 65536);       // [16][64] per-wave lsum (4 KB)
  const int t = threadIdx.x;
  const int wv = t >> 6;
  const int l = t & 63;
  const int c = l & 15, g = l >> 4;
  const int h = blockIdx.y;
  const int nq = blockIdx.x * 64;
  const int m0w = wv * 256;

  bf16x8 qf[4];
  #pragma unroll
  for (int s = 0; s < 4; ++s)
    qf[s] = *(const bf16x8*)&Qt[(h * 4096 + nq + s * 16 + c) * 32 + g * 8];

  f32x4 oh[4][2];
  #pragma unroll
  for (int s = 0; s < 4; ++s) {
    oh[s][0] = (f32x4){0.f, 0.f, 0.f, 0.f};
    oh[s][1] = (f32x4){0.f, 0.f, 0.f, 0.f};
  }
  float lsum[4] = {0.f, 0.f, 0.f, 0.f};

  const unsigned short* Kb  = Kt + (h * 4096 + m0w + c) * 32 + g * 8;
  const unsigned short* Vb0 = Vb + (h * 32 + c) * 4096 + m0w + g * 4;
  const unsigned short* Vb1 = Vb0 + 16 * 4096;

  #pragma unroll 4
  for (int j = 0; j < 16; ++j) {
    bf16x8 kf = *(const bf16x8*)&Kb[j * 512];
    bf16x4 vf0 = *(const bf16x4*)&Vb0[j * 16];
    bf16x4 vf1 = *(const bf16x4*)&Vb1[j * 16];
    #pragma unroll
    for (int s = 0; s < 4; ++s) {
      f32x4 z = {0.f, 0.f, 0.f, 0.f};
      f32x4 sv = __builtin_amdgcn_mfma_f32_16x16x32_bf16(kf, qf[s], z, 0, 0, 0);
      float e0 = fexp2(sv[0]);
      float e1 = fexp2(sv[1]);
      float e2 = fexp2(sv[2]);
      float e3 = fexp2(sv[3]);
      lsum[s] += (e0 + e1) + (e2 + e3);
      union { unsigned u[2]; bf16x4 v; } pu;
      pu.u[0] = __builtin_amdgcn_perm(fbits(e1), fbits(e0), 0x07060302);
      pu.u[1] = __builtin_amdgcn_perm(fbits(e3), fbits(e2), 0x07060302);
      oh[s][0] = pv_mfma(vf0, pu.v, oh[s][0]);
      oh[s][1] = pv_mfma(vf1, pu.v, oh[s][1]);
    }
  }

  // all 64 lanes hold the full wave lsum per query s*16+c after this
  #pragma unroll
  for (int s = 0; s < 4; ++s) {
    lsum[s] += __shfl_xor(lsum[s], 16, 64);
    lsum[s] += __shfl_xor(lsum[s], 32, 64);
  }

  // publish per-wave lsum once
  if (l < 16) {
    #pragma unroll
    for (int s = 0; s < 4; ++s) lf[wv * 64 + s * 16 + l] = lsum[s];
  }
  // round 1: waves 8-15 publish oh into slots 0-7
  if (wv >= 8) {
    float* slot = WS + (wv - 8) * 2048;
    #pragma unroll
    for (int s = 0; s < 4; ++s)
      #pragma unroll
      for (int hf = 0; hf < 2; ++hf)
        *(f32x4*)&slot[(s * 2 + hf) * 256 + l * 4] = oh[s][hf];
  }
  __syncthreads();
  // waves 0-7 accumulate; waves 4-7 republish their updated partials
  if (wv < 8) {
    float* slot = WS + wv * 2048;
    #pragma unroll
    for (int s = 0; s < 4; ++s)
      #pragma unroll
      for (int hf = 0; hf < 2; ++hf)
        oh[s][hf] += *(const f32x4*)&slot[(s * 2 + hf) * 256 + l * 4];
    if (wv >= 4) {
      #pragma unroll
      for (int s = 0; s < 4; ++s)
        #pragma unroll
        for (int hf = 0; hf < 2; ++hf)
          *(f32x4*)&slot[(s * 2 + hf) * 256 + l * 4] = oh[s][hf];
    }
  }
  __syncthreads();
  // waves 0-3 accumulate slots 4-7, publish finals into slots 0-3
  if (wv < 4) {
    float* src = WS + (wv + 4) * 2048;
    float* dst = WS + wv * 2048;
    #pragma unroll
    for (int s = 0; s < 4; ++s)
      #pragma unroll
      for (int hf = 0; hf < 2; ++hf) {
        oh[s][hf] += *(const f32x4*)&src[(s * 2 + hf) * 256 + l * 4];
        *(f32x4*)&dst[(s * 2 + hf) * 256 + l * 4] = oh[s][hf];
      }
  }
  __syncthreads();

  // final: sum 4 slots + 16 lsum partials, normalize, coalesced bf16 hi/lo out
  #pragma unroll
  for (int e = t; e < 2048; e += 1024) {
    int q = e >> 5, d = e & 31;
    int s = q >> 4, cc = q & 15, hf = d >> 4, gg = (d & 15) >> 2, ii = d & 3;
    int off = (s * 2 + hf) * 256 + (gg * 16 + cc) * 4 + ii;
    float s4 = WS[off] + WS[2048 + off] + WS[4096 + off] + WS[6144 + off];
    float li = 0.f;
    #pragma unroll
    for (int ww = 0; ww < 16; ++ww) li += lf[ww * 64 + q];
    float val = s4 / li;
    unsigned short hi = f2bf(val);
    float hfv = bfloat((unsigned)hi << 16);
    int idx = (nq + q) * 128 + h * 32 + d;
    Oth[idx] = hi;
    Otl[idx] = f2bf(val - hfv);
  }
}

// ---------- proj GEMM, split-bf16, W cast folded in-block ----------
__global__ __launch_bounds__(256)
void gemm_proj_kernel(const unsigned short* __restrict__ Oth,
                      const unsigned short* __restrict__ Otl,
                      const float* __restrict__ Wp, float* __restrict__ Y)
{
  const int t = threadIdx.x;
  const int w = t >> 6, c = t & 15, g = (t & 63) >> 4;
  const int n0 = blockIdx.x * 32;
  const int o_base = blockIdx.y * 64 + w * 16;
  f32x4 acc0 = {0.f, 0.f, 0.f, 0.f}, acc1 = {0.f, 0.f, 0.f, 0.f};
  #pragma unroll
  for (int ks = 0; ks < 4; ++ks) {
    const int ko = ks * 32 + g * 8;
    const float* wr = Wp + (o_base + c) * 128 + ko;
    union { unsigned u[4]; bf16x8 v; } ah, al;
    #pragma unroll
    for (int m = 0; m < 2; ++m) {
      f32x4 v = *(const f32x4*)&wr[m * 4];
      #pragma unroll
      for (int p = 0; p < 2; ++p) {
        unsigned hw = cvt_pk_bf16(v[2 * p], v[2 * p + 1]);
        float h0 = bfloat(hw << 16);
        float h1 = bfloat(hw & 0xFFFF0000u);
        ah.u[m * 2 + p] = hw;
        al.u[m * 2 + p] = cvt_pk_bf16(v[2 * p] - h0, v[2 * p + 1] - h1);
      }
    }
    bf16x8 bh0 = *(const bf16x8*)&Oth[(n0 + c) * 128 + ko];
    bf16x8 bl0 = *(const bf16x8*)&Otl[(n0 + c) * 128 + ko];
    bf16x8 bh1 = *(const bf16x8*)&Oth[(n0 + 16 + c) * 128 + ko];
    bf16x8 bl1 = *(const bf16x8*)&Otl[(n0 + 16 + c) * 128 + ko];
    acc0 = __builtin_amdgcn_mfma_f32_16x16x32_bf16(al.v, bh0, acc0, 0, 0, 0);
    acc0 = __builtin_amdgcn_mfma_f32_16x16x32_bf16(ah.v, bl0, acc0, 0, 0, 0);
    acc0 = __builtin_amdgcn_mfma_f32_16x16x32_bf16(ah.v, bh0, acc0, 0, 0, 0);
    acc1 = __builtin_amdgcn_mfma_f32_16x16x32_bf16(al.v, bh1, acc1, 0, 0, 0);
    acc1 = __builtin_amdgcn_mfma_f32_16x16x32_bf16(ah.v, bl1, acc1, 0, 0, 0);
    acc1 = __builtin_amdgcn_mfma_f32_16x16x32_bf16(ah.v, bh1, acc1, 0, 0, 0);
  }
  #pragma unroll
  for (int i = 0; i < 4; ++i) {
    Y[(o_base + 4 * g + i) * 4096 + n0 + c] = acc0[i];
    Y[(o_base + 4 * g + i) * 4096 + n0 + 16 + c] = acc1[i];
  }
}

extern "C" void kernel_launch(void* const* d_in, const int* in_sizes, int n_in,
                              void* d_out, int out_size, void* d_ws, size_t ws_size,
                              hipStream_t stream) {
  const float* xq    = (const float*)d_in[0];
  const float* xkv   = (const float*)d_in[1];
  const float* wqkv  = (const float*)d_in[2];
  const float* wdw   = (const float*)d_in[3];
  const float* wproj = (const float*)d_in[4];
  const float* temp  = (const float*)d_in[5];
  float* out = (float*)d_out;

  char* ws = (char*)d_ws;
  unsigned short* t16 = (unsigned short*)ws;                 // 3 MB  [384][4096]
  unsigned short* qt  = (unsigned short*)(ws + 3145728);     // 1 MB  [4][4096][32]
  unsigned short* kt  = (unsigned short*)(ws + 4194304);     // 1 MB
  unsigned short* vb  = (unsigned short*)(ws + 5242880);     // 1 MB  [128][4096]
  unsigned short* oth = (unsigned short*)(ws + 6291456);     // 1 MB  [4096][128]
  unsigned short* otl = (unsigned short*)(ws + 7340032);     // 1 MB

  qkvT_kernel<<<dim3(128, 6), 256, 0, stream>>>(xq, xkv, wqkv, t16);
  dwconv_kernel<<<dim3(1536), 256, 0, stream>>>(t16, wdw, temp, qt, kt, vb);
  attn_kernel<<<dim3(64, 4), 1024, 69632, stream>>>(qt, kt, vb, oth, otl);
  gemm_proj_kernel<<<dim3(128, 2), 256, 0, stream>>>(oth, otl, wproj, out);
}